// Round 4
// baseline (352.807 us; speedup 1.0000x reference)
//
#include <hip/hip_runtime.h>
#include <hip/hip_fp16.h>
#include <stdint.h>

typedef float floatx4 __attribute__((ext_vector_type(4)));
typedef short short8 __attribute__((ext_vector_type(8)));

constexpr int I_SZ = 256, O_SZ = 256, NCOL = 512, B_SZ = 4096;
constexpr int KSTEPS = 264;           // 256 RBF steps + 8 silu steps
constexpr float GSTEP = 4.0f / 7.0f;  // linspace(-2,2,8) step
constexpr float NLOG2E = -1.44269504088896f;

// pack two fp32 -> two bf16 (truncate) in one v_perm_b32
__device__ __forceinline__ uint32_t pk_bf16(float lo, float hi) {
  return __builtin_amdgcn_perm(__float_as_uint(hi), __float_as_uint(lo), 0x07060302u);
}
__device__ __forceinline__ short rne_bf16(float f) {
  uint32_t u = __float_as_uint(f);
  return (short)((u + 0x7FFFu + ((u >> 16) & 1u)) >> 16);
}
__device__ __forceinline__ float silu_f(float a) {
  return a * __builtin_amdgcn_rcpf(1.f + __builtin_amdgcn_exp2f(a * NLOG2E));
}

// ================= fused prelude: pack (4224 blk) + transpose (512 blk) + bias (128 blk) =================
// wpack layout is now LINEAR: wpack[s][n][k], k = u*8+v (RBF) / kp (silu). No swizzle (no LDS in gemm).
__global__ void prelude(const float* __restrict__ rw, const float* __restrict__ cw,
                        const float* __restrict__ swre, const float* __restrict__ swim,
                        const float* __restrict__ bre, const float* __restrict__ bim,
                        const float* __restrict__ xre, const float* __restrict__ xim,
                        short* __restrict__ wpack, float* __restrict__ bsum,
                        __half* __restrict__ xT) {
  __shared__ float tile[64][65];
  const int bid = blockIdx.x, tid = threadIdx.x;

  if (bid < 4224) {
    // ---- weight pack: idx -> (kb, n, g); 8 consecutive k per thread ----
    int idx = bid * 256 + tid;
    int kb = idx >> 12;                 // / (512*8)
    int rem = idx & 4095;
    int n = rem >> 3, g = rem & 7;
    int o = n >> 1, c = n & 1;
    float w[8];
    if (kb < 256) {
      const float* W = (c ? cw : rw) + ((((size_t)kb * O_SZ + o) << 3) + g << 3);
      float4 a = *(const float4*)W;
      float4 b = *(const float4*)(W + 4);
      w[0] = a.x; w[1] = a.y; w[2] = a.z; w[3] = a.w;
      w[4] = b.x; w[5] = b.y; w[6] = b.z; w[7] = b.w;
    } else {
      int kp0 = ((kb - 256) << 6) + (g << 3);
      #pragma unroll
      for (int e = 0; e < 8; ++e) {
        int kp = kp0 + e, i = kp >> 1, ci = kp & 1;
        float a = swre[i * O_SZ + o], b = swim[i * O_SZ + o];
        w[e] = (c == 0) ? (ci == 0 ? a : -b) : (ci == 0 ? b : a);
      }
    }
    uint32_t h[8];
    #pragma unroll
    for (int e = 0; e < 8; ++e) h[e] = (uint32_t)(uint16_t)rne_bf16(w[e]);
    uint4 val = make_uint4(h[0] | (h[1] << 16), h[2] | (h[3] << 16),
                           h[4] | (h[5] << 16), h[6] | (h[7] << 16));
    *(uint4*)(wpack + (size_t)idx * 8) = val;
  } else if (bid < 4736) {
    // ---- x transpose: xT[c][i][b] fp16 ----
    int tb = bid - 4224;
    int bt = tb & 63, it = (tb >> 6) & 3, c = tb >> 8;
    const float* src = (c ? xim : xre);
    int b0 = bt << 6, i0 = it << 6;
    int il = tid & 63, bh = tid >> 6;
    #pragma unroll
    for (int k = 0; k < 16; ++k) {
      int bl = bh + (k << 2);
      tile[bl][il] = src[(size_t)(b0 + bl) * I_SZ + i0 + il];
    }
    __syncthreads();
    int bl2 = tid & 63, ih = tid >> 6;
    __half* dst = xT + ((size_t)c * I_SZ + i0) * B_SZ + b0;
    #pragma unroll
    for (int k = 0; k < 16; ++k) {
      int il2 = ih + (k << 2);
      dst[(size_t)il2 * B_SZ + bl2] = __float2half(tile[bl2][il2]);
    }
  } else {
    // ---- bias column sums: one wave per n ----
    int w = tid >> 6, l = tid & 63;
    int n = (bid - 4736) * 4 + w;
    int o = n >> 1;
    const float* src = ((n & 1) ? bim : bre) + o;
    float s = 0.f;
    #pragma unroll
    for (int a = 0; a < 4; ++a) s += src[(size_t)(a * 64 + l) * O_SZ];
    #pragma unroll
    for (int off = 32; off; off >>= 1) s += __shfl_down(s, off, 64);
    if (l == 0) bsum[n] = s;
  }
}

// ================= barrier-free GEMM =================
// grid 1024 = kch(8, low bits -> XCD-aligned) x mt(32) x nt(4). Block 256 = 4 waves.
// Wave w owns rows b0 + w*32 .. +31 (2 m-tiles), all 128 cols (8 n-tiles).
// A fragments built in registers from xT; B fragments loaded straight from wpack (L1/L2).
// NO LDS, NO __syncthreads in the K-loop.
__global__ __launch_bounds__(256, 2) void cvkan_gemm(
    const float* __restrict__ xre, const float* __restrict__ xim,
    const __half* __restrict__ xT,
    const short* __restrict__ wpack, const float* __restrict__ bsum,
    float* __restrict__ out) {
  const int tid = threadIdx.x, bid = blockIdx.x;
  const int kch = bid & 7;
  const int mn = bid >> 3;
  const int mt = mn >> 2, nt = mn & 3;
  const int b0 = mt * 128, n0 = nt * 128;
  const int w = tid >> 6, l = tid & 63;
  const int lm = l & 15, q = l >> 4;
  const int row0 = b0 + w * 32 + lm;    // + mm*16

  const __half* xTre = xT;
  const __half* xTim = xT + (size_t)I_SZ * B_SZ;

  floatx4 acc[2][8] = {};

  for (int j = 0; j < 33; ++j) {
    const int s = (j < 32) ? (kch * 32 + j) : (256 + kch);

    // --- issue all 16 B-fragment loads first (latency covered by A-build below) ---
    // frag (nn,kh): lanes (lm,q) read 16B at col = n0+nn*16+lm, k-bytes (q+4kh)*16 -> 64B-coalesced
    const short* bbase = wpack + ((size_t)s * NCOL + n0) * 64 + (q << 3);
    short8 bf[8][2];
    #pragma unroll
    for (int nn = 0; nn < 8; ++nn) {
      const short* p = bbase + ((nn * 16 + lm) << 6);
      bf[nn][0] = *(const short8*)p;
      bf[nn][1] = *(const short8*)(p + 32);
    }

    // --- A fragments in registers ---
    short8 af[2][2];
    if (j < 32) {
      #pragma unroll
      for (int mm = 0; mm < 2; ++mm) {
        const int row = row0 + mm * 16;
        float xr = __half2float(xTre[(size_t)s * B_SZ + row]);
        float xi = __half2float(xTim[(size_t)s * B_SZ + row]);
        float eiv[8];
        #pragma unroll
        for (int v = 0; v < 8; ++v) {
          float d = xi - (-2.0f + v * GSTEP);
          eiv[v] = __builtin_amdgcn_exp2f(d * d * NLOG2E);
        }
        float d0 = xr - (-2.0f + q * GSTEP);
        float d1 = xr - (-2.0f + (q + 4) * GSTEP);
        float er0 = __builtin_amdgcn_exp2f(d0 * d0 * NLOG2E);
        float er1 = __builtin_amdgcn_exp2f(d1 * d1 * NLOG2E);
        union { short8 v; uint32_t u[4]; } a0, a1;
        #pragma unroll
        for (int t = 0; t < 4; ++t) {
          a0.u[t] = pk_bf16(er0 * eiv[2 * t], er0 * eiv[2 * t + 1]);
          a1.u[t] = pk_bf16(er1 * eiv[2 * t], er1 * eiv[2 * t + 1]);
        }
        af[mm][0] = a0.v;
        af[mm][1] = a1.v;
      }
    } else {
      const int sl = kch;               // silu step: k -> kp = sl*64 + u*8 + v; i = kp>>1, ci = kp&1
      #pragma unroll
      for (int mm = 0; mm < 2; ++mm) {
        const int row = row0 + mm * 16;
        #pragma unroll
        for (int kh = 0; kh < 2; ++kh) {
          int i0 = sl * 32 + (q + kh * 4) * 4;
          float4 fr = *(const float4*)(xre + (size_t)row * I_SZ + i0);
          float4 fi = *(const float4*)(xim + (size_t)row * I_SZ + i0);
          union { short8 v; uint32_t u[4]; } a;
          a.u[0] = pk_bf16(silu_f(fr.x), silu_f(fi.x));
          a.u[1] = pk_bf16(silu_f(fr.y), silu_f(fi.y));
          a.u[2] = pk_bf16(silu_f(fr.z), silu_f(fi.z));
          a.u[3] = pk_bf16(silu_f(fr.w), silu_f(fi.w));
          af[mm][kh] = a.v;
        }
      }
    }

    // --- MFMA: 32 x 16x16x32 ---
    #pragma unroll
    for (int mm = 0; mm < 2; ++mm)
      #pragma unroll
      for (int nn = 0; nn < 8; ++nn) {
        acc[mm][nn] = __builtin_amdgcn_mfma_f32_16x16x32_bf16(af[mm][0], bf[nn][0], acc[mm][nn], 0, 0, 0);
        acc[mm][nn] = __builtin_amdgcn_mfma_f32_16x16x32_bf16(af[mm][1], bf[nn][1], acc[mm][nn], 0, 0, 0);
      }
  }

  // --- epilogue: C/D col=lane&15, row=q*4+reg; bias added by chunk-7 only ---
  #pragma unroll
  for (int nn = 0; nn < 8; ++nn) {
    int col = n0 + nn * 16 + lm;
    float bv = (kch == 7) ? bsum[col] : 0.0f;
    #pragma unroll
    for (int mm = 0; mm < 2; ++mm) {
      int r0 = b0 + w * 32 + mm * 16 + (q << 2);
      #pragma unroll
      for (int r2 = 0; r2 < 4; ++r2)
        atomicAdd(out + (size_t)(r0 + r2) * NCOL + col, acc[mm][nn][r2] + bv);
    }
  }
}

extern "C" void kernel_launch(void* const* d_in, const int* in_sizes, int n_in,
                              void* d_out, int out_size, void* d_ws, size_t ws_size,
                              hipStream_t stream) {
  const float* xre  = (const float*)d_in[0];
  const float* xim  = (const float*)d_in[1];
  const float* rw   = (const float*)d_in[2];
  const float* cw   = (const float*)d_in[3];
  const float* swre = (const float*)d_in[4];
  const float* swim = (const float*)d_in[5];
  const float* bre  = (const float*)d_in[6];
  const float* bim  = (const float*)d_in[7];
  float* out = (float*)d_out;

  size_t wpack_bytes = (size_t)KSTEPS * NCOL * 64 * 2;   // 16.5 MiB
  short* wpack = (short*)d_ws;
  float* bsum  = (float*)((char*)d_ws + wpack_bytes);
  __half* xT   = (__half*)((char*)d_ws + wpack_bytes + 4096);  // 4 MiB

  hipMemsetAsync(d_out, 0, (size_t)B_SZ * NCOL * sizeof(float), stream);
  prelude<<<4864, 256, 0, stream>>>(rw, cw, swre, swim, bre, bim, xre, xim, wpack, bsum, xT);
  cvkan_gemm<<<1024, 256, 0, stream>>>(xre, xim, xT, wpack, bsum, out);
}

// Round 5
// 242.594 us; speedup vs baseline: 1.4543x; 1.4543x over previous
//
#include <hip/hip_runtime.h>
#include <hip/hip_fp16.h>
#include <stdint.h>

typedef float floatx4 __attribute__((ext_vector_type(4)));
typedef short short8 __attribute__((ext_vector_type(8)));

constexpr int I_SZ = 256, O_SZ = 256, NCOL = 512, B_SZ = 4096;
constexpr int KSTEPS = 264;           // 256 RBF steps + 8 silu steps
constexpr float GSTEP = 4.0f / 7.0f;  // linspace(-2,2,8) step
constexpr float NLOG2E = -1.44269504088896f;

__device__ __forceinline__ uint32_t pk_bf16(float lo, float hi) {
  return __builtin_amdgcn_perm(__float_as_uint(hi), __float_as_uint(lo), 0x07060302u);
}
__device__ __forceinline__ short rne_bf16(float f) {
  uint32_t u = __float_as_uint(f);
  return (short)((u + 0x7FFFu + ((u >> 16) & 1u)) >> 16);
}
__device__ __forceinline__ float silu_f(float a) {
  return a * __builtin_amdgcn_rcpf(1.f + __builtin_amdgcn_exp2f(a * NLOG2E));
}
__device__ __forceinline__ void gload_lds16(const void* g, void* l) {
  __builtin_amdgcn_global_load_lds((const __attribute__((address_space(1))) void*)g,
                                   (__attribute__((address_space(3))) void*)l,
                                   16, 0, 0);
}

// ===== prelude: weight pack (swizzled, 4224 blk) + xT transpose (512) + bias (128) + out-zero (512) =====
// wpack[s][n][gp][e] bf16, gp = g ^ (n&7)  (conflict-free frag reads, contiguous DMA)
__global__ void prelude(const float* __restrict__ rw, const float* __restrict__ cw,
                        const float* __restrict__ swre, const float* __restrict__ swim,
                        const float* __restrict__ bre, const float* __restrict__ bim,
                        const float* __restrict__ xre, const float* __restrict__ xim,
                        short* __restrict__ wpack, float* __restrict__ bsum,
                        __half* __restrict__ xT, float* __restrict__ out) {
  __shared__ float tile[64][65];
  const int bid = blockIdx.x, tid = threadIdx.x;

  if (bid < 4224) {
    int idx = bid * 256 + tid;                  // (kb, n, gp): 264*512*8
    int kb = idx >> 12;
    int rem = idx & 4095;
    int n = rem >> 3, gp = rem & 7;
    int g = gp ^ (n & 7);
    int o = n >> 1, c = n & 1;
    float w[8];
    if (kb < 256) {
      const float* W = (c ? cw : rw) + (((size_t)kb * O_SZ + o) << 6) + (g << 3);
      float4 a = *(const float4*)W;
      float4 b = *(const float4*)(W + 4);
      w[0] = a.x; w[1] = a.y; w[2] = a.z; w[3] = a.w;
      w[4] = b.x; w[5] = b.y; w[6] = b.z; w[7] = b.w;
    } else {
      int kp0 = ((kb - 256) << 6) + (g << 3);
      #pragma unroll
      for (int e = 0; e < 8; ++e) {
        int kp = kp0 + e, i = kp >> 1, ci = kp & 1;
        float a = swre[i * O_SZ + o], b = swim[i * O_SZ + o];
        w[e] = (c == 0) ? (ci == 0 ? a : -b) : (ci == 0 ? b : a);
      }
    }
    uint32_t h[8];
    #pragma unroll
    for (int e = 0; e < 8; ++e) h[e] = (uint32_t)(uint16_t)rne_bf16(w[e]);
    uint4 val = make_uint4(h[0] | (h[1] << 16), h[2] | (h[3] << 16),
                           h[4] | (h[5] << 16), h[6] | (h[7] << 16));
    *(uint4*)(wpack + (size_t)idx * 8) = val;
  } else if (bid < 4736) {
    int tb = bid - 4224;                        // xT[c][i][b] fp16
    int bt = tb & 63, it = (tb >> 6) & 3, c = tb >> 8;
    const float* src = (c ? xim : xre);
    int b0 = bt << 6, i0 = it << 6;
    int il = tid & 63, bh = tid >> 6;
    #pragma unroll
    for (int k = 0; k < 16; ++k) {
      int bl = bh + (k << 2);
      tile[bl][il] = src[(size_t)(b0 + bl) * I_SZ + i0 + il];
    }
    __syncthreads();
    int bl2 = tid & 63, ih = tid >> 6;
    __half* dst = xT + ((size_t)c * I_SZ + i0) * B_SZ + b0;
    #pragma unroll
    for (int k = 0; k < 16; ++k) {
      int il2 = ih + (k << 2);
      dst[(size_t)il2 * B_SZ + bl2] = __float2half(tile[bl2][il2]);
    }
  } else if (bid < 4864) {
    int w = tid >> 6, l = tid & 63;             // bias sums, one wave per n
    int n = (bid - 4736) * 4 + w;
    int o = n >> 1;
    const float* src = ((n & 1) ? bim : bre) + o;
    float s = 0.f;
    #pragma unroll
    for (int a = 0; a < 4; ++a) s += src[(size_t)(a * 64 + l) * O_SZ];
    #pragma unroll
    for (int off = 32; off; off >>= 1) s += __shfl_down(s, off, 64);
    if (l == 0) bsum[n] = s;
  } else {
    int z = bid - 4864;                         // zero d_out: 512 blk * 16 KB
    float4* o4 = (float4*)out;
    float4 zv = {0.f, 0.f, 0.f, 0.f};
    #pragma unroll
    for (int k = 0; k < 4; ++k) o4[(size_t)z * 1024 + k * 256 + tid] = zv;
  }
}

// ===== pipelined GEMM =====
// grid 1024 = kch(8, low bits -> XCD-aligned) x mt(16) x nt(8). Block 256 = 4 waves.
// Block tile 256 rows x 64 cols; wave w owns rows [b0+w*64, +64), all 64 cols.
// A fragments in registers (exp-built from xT); B double-buffered in LDS via global_load_lds DMA.
// ONE barrier per step; DMA(j+1) stays in flight across the whole step (drained at next barrier).
__global__ __launch_bounds__(256, 2) void cvkan_gemm(
    const float* __restrict__ xre, const float* __restrict__ xim,
    const __half* __restrict__ xT,
    const short* __restrict__ wpack, const float* __restrict__ bsum,
    float* __restrict__ out) {
  __shared__ __align__(16) short Bs[2][64 * 64];   // 2 x 8 KB, [col][gp][e], gp = g ^ (col&7)

  const int tid = threadIdx.x, bid = blockIdx.x;
  const int kch = bid & 7;
  const int rest = bid >> 3;
  const int mt = rest & 15, nt = rest >> 4;
  const int b0 = mt * 256, n0 = nt * 64;
  const int w = tid >> 6, l = tid & 63;
  const int lm = l & 15, q = l >> 4;
  const int row0 = b0 + w * 64 + lm;    // + mm*16

  const __half* xTre = xT;
  const __half* xTim = xT + (size_t)I_SZ * B_SZ;

  floatx4 acc[4][4] = {};

  // prologue: stage step 0 into buf 0 (wave w copies its 2 KB quarter)
  {
    const short* slab = wpack + ((size_t)(kch * 32) * NCOL + n0) * 64 + (w << 10) + (l << 3);
    short* dst = &Bs[0][0] + (w << 10);          // wave-uniform; HW adds lane*16B
    gload_lds16(slab, dst);
    gload_lds16(slab + 512, dst + 512);
  }

  for (int j = 0; j < 33; ++j) {
    const int s = (j < 32) ? (kch * 32 + j) : (256 + kch);

    __syncthreads();   // drains DMA(j) (in flight for a full step) + last step's ds_reads

    // --- early A-source loads for step j (issued BEFORE next DMA so their wait leaves it in flight) ---
    float xr[4], xi[4];
    if (j < 32) {
      #pragma unroll
      for (int mm = 0; mm < 4; ++mm) {
        const int row = row0 + mm * 16;
        xr[mm] = __half2float(xTre[(size_t)s * B_SZ + row]);
        xi[mm] = __half2float(xTim[(size_t)s * B_SZ + row]);
      }
    }

    // --- stage step j+1 into the other buffer (drained at NEXT barrier, not this step) ---
    if (j < 32) {
      const int s1 = (j < 31) ? (s + 1) : (256 + kch);
      const short* slab = wpack + ((size_t)s1 * NCOL + n0) * 64 + (w << 10) + (l << 3);
      short* dst = &Bs[(j + 1) & 1][0] + (w << 10);
      gload_lds16(slab, dst);
      gload_lds16(slab + 512, dst + 512);
    }

    // --- B fragments from current buffer: col c = nn*16+lm, k-group kk = q / q+4, swizzled ---
    short8 bf[4][2];
    const short* bp0 = &Bs[j & 1][0];
    #pragma unroll
    for (int nn = 0; nn < 4; ++nn) {
      int c = nn * 16 + lm;
      const short* bp = bp0 + (c << 6);
      bf[nn][0] = *(const short8*)(bp + ((q       ^ (c & 7)) << 3));
      bf[nn][1] = *(const short8*)(bp + (((q + 4) ^ (c & 7)) << 3));
    }

    // --- A fragments in registers ---
    short8 af[4][2];
    if (j < 32) {
      #pragma unroll
      for (int mm = 0; mm < 4; ++mm) {
        float eiv[8];
        #pragma unroll
        for (int v = 0; v < 8; ++v) {
          float d = xi[mm] - (-2.0f + v * GSTEP);
          eiv[v] = __builtin_amdgcn_exp2f(d * d * NLOG2E);
        }
        float d0 = xr[mm] - (-2.0f + q * GSTEP);
        float d1 = xr[mm] - (-2.0f + (q + 4) * GSTEP);
        float er0 = __builtin_amdgcn_exp2f(d0 * d0 * NLOG2E);
        float er1 = __builtin_amdgcn_exp2f(d1 * d1 * NLOG2E);
        union { short8 v; uint32_t u[4]; } a0, a1;
        #pragma unroll
        for (int t = 0; t < 4; ++t) {
          a0.u[t] = pk_bf16(er0 * eiv[2 * t], er0 * eiv[2 * t + 1]);
          a1.u[t] = pk_bf16(er1 * eiv[2 * t], er1 * eiv[2 * t + 1]);
        }
        af[mm][0] = a0.v;
        af[mm][1] = a1.v;
      }
    } else {
      const int sl = kch;               // silu step: kp = sl*64 + kk*8 + e; i = kp>>1, ci = kp&1
      #pragma unroll
      for (int mm = 0; mm < 4; ++mm) {
        const int row = row0 + mm * 16;
        #pragma unroll
        for (int kh = 0; kh < 2; ++kh) {
          int i0 = sl * 32 + (q + kh * 4) * 4;
          float4 fr = *(const float4*)(xre + (size_t)row * I_SZ + i0);
          float4 fi = *(const float4*)(xim + (size_t)row * I_SZ + i0);
          union { short8 v; uint32_t u[4]; } a;
          a.u[0] = pk_bf16(silu_f(fr.x), silu_f(fi.x));
          a.u[1] = pk_bf16(silu_f(fr.y), silu_f(fi.y));
          a.u[2] = pk_bf16(silu_f(fr.z), silu_f(fi.z));
          a.u[3] = pk_bf16(silu_f(fr.w), silu_f(fi.w));
          af[mm][kh] = a.v;
        }
      }
    }

    // --- MFMA: 4 mm x 4 nn x 2 kh ---
    #pragma unroll
    for (int mm = 0; mm < 4; ++mm)
      #pragma unroll
      for (int nn = 0; nn < 4; ++nn) {
        acc[mm][nn] = __builtin_amdgcn_mfma_f32_16x16x32_bf16(af[mm][0], bf[nn][0], acc[mm][nn], 0, 0, 0);
        acc[mm][nn] = __builtin_amdgcn_mfma_f32_16x16x32_bf16(af[mm][1], bf[nn][1], acc[mm][nn], 0, 0, 0);
      }
  }

  // --- epilogue: C/D col=lane&15, row=q*4+reg; bias added by chunk-7 only ---
  #pragma unroll
  for (int nn = 0; nn < 4; ++nn) {
    int col = n0 + nn * 16 + lm;
    float bv = (kch == 7) ? bsum[col] : 0.0f;
    #pragma unroll
    for (int mm = 0; mm < 4; ++mm) {
      int r0 = b0 + w * 64 + mm * 16 + (q << 2);
      #pragma unroll
      for (int r2 = 0; r2 < 4; ++r2)
        atomicAdd(out + (size_t)(r0 + r2) * NCOL + col, acc[mm][nn][r2] + bv);
    }
  }
}

extern "C" void kernel_launch(void* const* d_in, const int* in_sizes, int n_in,
                              void* d_out, int out_size, void* d_ws, size_t ws_size,
                              hipStream_t stream) {
  const float* xre  = (const float*)d_in[0];
  const float* xim  = (const float*)d_in[1];
  const float* rw   = (const float*)d_in[2];
  const float* cw   = (const float*)d_in[3];
  const float* swre = (const float*)d_in[4];
  const float* swim = (const float*)d_in[5];
  const float* bre  = (const float*)d_in[6];
  const float* bim  = (const float*)d_in[7];
  float* out = (float*)d_out;

  size_t wpack_bytes = (size_t)KSTEPS * NCOL * 64 * 2;   // 16.5 MiB
  short* wpack = (short*)d_ws;
  float* bsum  = (float*)((char*)d_ws + wpack_bytes);
  __half* xT   = (__half*)((char*)d_ws + wpack_bytes + 4096);  // 4 MiB

  prelude<<<5376, 256, 0, stream>>>(rw, cw, swre, swim, bre, bim, xre, xim,
                                    wpack, bsum, xT, out);
  cvkan_gemm<<<1024, 256, 0, stream>>>(xre, xim, xT, wpack, bsum, out);
}

// Round 6
// 232.974 us; speedup vs baseline: 1.5144x; 1.0413x over previous
//
#include <hip/hip_runtime.h>
#include <stdint.h>

typedef float floatx4 __attribute__((ext_vector_type(4)));
typedef _Float16 half8 __attribute__((ext_vector_type(8)));
typedef _Float16 half2t __attribute__((ext_vector_type(2)));

constexpr int I_SZ = 256, O_SZ = 256, NCOL = 512, B_SZ = 4096;
constexpr int KSTEPS = 264;           // 256 RBF steps + 8 silu steps
constexpr float GSTEP = 4.0f / 7.0f;  // linspace(-2,2,8) step
constexpr float NLOG2E = -1.44269504088896f;

__device__ __forceinline__ float silu_f(float a) {
  return a * __builtin_amdgcn_rcpf(1.f + __builtin_amdgcn_exp2f(a * NLOG2E));
}
__device__ __forceinline__ void gload_lds16(const void* g, void* l) {
  __builtin_amdgcn_global_load_lds((const __attribute__((address_space(1))) void*)g,
                                   (__attribute__((address_space(3))) void*)l,
                                   16, 0, 0);
}

union H8 { half8 v; half2t h[4]; uint32_t u[4]; };

// ===== prelude =====
// seg A [0,4224): wpack[s][n][gp][e] f16, gp = g ^ (n&7)
// seg B [4224,4480): eivT[i][b][8] f16 + erqT[i][b][8] f16 (pairs (er_q, er_{q+4}) at dword q)
// seg C [4480,4992): sTab[b][kp] f16, kp = 2i+ci (silu values)
// seg D [4992,5120): bias column sums
// seg E [5120,5632): zero d_out
__global__ void prelude(const float* __restrict__ rw, const float* __restrict__ cw,
                        const float* __restrict__ swre, const float* __restrict__ swim,
                        const float* __restrict__ bre, const float* __restrict__ bim,
                        const float* __restrict__ xre, const float* __restrict__ xim,
                        _Float16* __restrict__ wpack, float* __restrict__ bsum,
                        _Float16* __restrict__ eivT, _Float16* __restrict__ erqT,
                        _Float16* __restrict__ sTab, float* __restrict__ out) {
  __shared__ float tileR[64][65];
  __shared__ float tileI[64][65];
  const int bid = blockIdx.x, tid = threadIdx.x;

  if (bid < 4224) {
    int idx = bid * 256 + tid;                  // (kb, n, gp): 264*512*8
    int kb = idx >> 12;
    int rem = idx & 4095;
    int n = rem >> 3, gp = rem & 7;
    int g = gp ^ (n & 7);
    int o = n >> 1, c = n & 1;
    float w[8];
    if (kb < 256) {
      const float* W = (c ? cw : rw) + (((size_t)kb * O_SZ + o) << 6) + (g << 3);
      float4 a = *(const float4*)W;
      float4 b = *(const float4*)(W + 4);
      w[0] = a.x; w[1] = a.y; w[2] = a.z; w[3] = a.w;
      w[4] = b.x; w[5] = b.y; w[6] = b.z; w[7] = b.w;
    } else {
      int kp0 = ((kb - 256) << 6) + (g << 3);
      #pragma unroll
      for (int e = 0; e < 8; ++e) {
        int kp = kp0 + e, i = kp >> 1, ci = kp & 1;
        float a = swre[i * O_SZ + o], b = swim[i * O_SZ + o];
        w[e] = (c == 0) ? (ci == 0 ? a : -b) : (ci == 0 ? b : a);
      }
    }
    H8 val;
    #pragma unroll
    for (int e = 0; e < 8; ++e) val.v[e] = (_Float16)w[e];
    *(H8*)(wpack + (size_t)idx * 8) = val;
  } else if (bid < 4480) {
    // ---- exp tables: tile 64 i x 64 b ----
    int tb = bid - 4224;
    int bt = tb & 63, it = tb >> 6;
    int b0 = bt << 6, i0 = it << 6;
    int il = tid & 63, bh = tid >> 6;
    #pragma unroll
    for (int k = 0; k < 16; ++k) {
      int bl = bh + (k << 2);
      tileR[bl][il] = xre[(size_t)(b0 + bl) * I_SZ + i0 + il];
      tileI[bl][il] = xim[(size_t)(b0 + bl) * I_SZ + i0 + il];
    }
    __syncthreads();
    #pragma unroll
    for (int k = 0; k < 16; ++k) {
      int p = k * 256 + tid;
      int i_l = p >> 6, b_l = p & 63;
      float xr = tileR[b_l][i_l];
      float xi = tileI[b_l][i_l];
      float eru[8], eiv[8];
      #pragma unroll
      for (int g = 0; g < 8; ++g) {
        float dr = xr - (-2.0f + g * GSTEP);
        float di = xi - (-2.0f + g * GSTEP);
        eru[g] = __builtin_amdgcn_exp2f(dr * dr * NLOG2E);
        eiv[g] = __builtin_amdgcn_exp2f(di * di * NLOG2E);
      }
      size_t base = ((size_t)(i0 + i_l) * B_SZ + b0 + b_l) * 8;
      H8 ev, eq;
      #pragma unroll
      for (int g = 0; g < 8; ++g) ev.v[g] = (_Float16)eiv[g];
      #pragma unroll
      for (int q = 0; q < 4; ++q) { eq.v[2 * q] = (_Float16)eru[q]; eq.v[2 * q + 1] = (_Float16)eru[q + 4]; }
      *(H8*)(eivT + base) = ev;
      *(H8*)(erqT + base) = eq;
    }
  } else if (bid < 4992) {
    // ---- silu table: sTab[b][2i+ci] ----
    int tg = (bid - 4480) * 256 + tid;
    int b = tg >> 5, io = (tg & 31) << 3;
    const float* pr = xre + (size_t)b * I_SZ + io;
    const float* pi = xim + (size_t)b * I_SZ + io;
    float4 r0 = *(const float4*)pr, r1 = *(const float4*)(pr + 4);
    float4 q0 = *(const float4*)pi, q1 = *(const float4*)(pi + 4);
    H8 lo, hi;
    lo.v[0] = (_Float16)silu_f(r0.x); lo.v[1] = (_Float16)silu_f(q0.x);
    lo.v[2] = (_Float16)silu_f(r0.y); lo.v[3] = (_Float16)silu_f(q0.y);
    lo.v[4] = (_Float16)silu_f(r0.z); lo.v[5] = (_Float16)silu_f(q0.z);
    lo.v[6] = (_Float16)silu_f(r0.w); lo.v[7] = (_Float16)silu_f(q0.w);
    hi.v[0] = (_Float16)silu_f(r1.x); hi.v[1] = (_Float16)silu_f(q1.x);
    hi.v[2] = (_Float16)silu_f(r1.y); hi.v[3] = (_Float16)silu_f(q1.y);
    hi.v[4] = (_Float16)silu_f(r1.z); hi.v[5] = (_Float16)silu_f(q1.z);
    hi.v[6] = (_Float16)silu_f(r1.w); hi.v[7] = (_Float16)silu_f(q1.w);
    _Float16* dst = sTab + (size_t)b * 512 + 2 * io;
    *(H8*)dst = lo;
    *(H8*)(dst + 8) = hi;
  } else if (bid < 5120) {
    int w = tid >> 6, l = tid & 63;             // bias sums, one wave per n
    int n = (bid - 4992) * 4 + w;
    int o = n >> 1;
    const float* src = ((n & 1) ? bim : bre) + o;
    float s = 0.f;
    #pragma unroll
    for (int a = 0; a < 4; ++a) s += src[(size_t)(a * 64 + l) * O_SZ];
    #pragma unroll
    for (int off = 32; off; off >>= 1) s += __shfl_down(s, off, 64);
    if (l == 0) bsum[n] = s;
  } else {
    int z = bid - 5120;                         // zero d_out: 512 blk * 16 KB
    float4* o4 = (float4*)out;
    float4 zv = {0.f, 0.f, 0.f, 0.f};
    #pragma unroll
    for (int k = 0; k < 4; ++k) o4[(size_t)z * 1024 + k * 256 + tid] = zv;
  }
}

// ===== pipelined GEMM, table-driven A (no transcendentals in K-loop) =====
// grid 512 = kch(8, low bits) x mt(8) x nt(8). Block 256 = 4 waves; tile 512 rows x 64 cols.
// Wave w owns rows [b0 + w*128, +128) (8 m-frags), all 64 cols (4 n-frags).
// B double-buffered in LDS via DMA (1 barrier/step, DMA in flight a full step).
__global__ __launch_bounds__(256, 2) void cvkan_gemm(
    const _Float16* __restrict__ eivT, const _Float16* __restrict__ erqT,
    const _Float16* __restrict__ sTab,
    const _Float16* __restrict__ wpack, const float* __restrict__ bsum,
    float* __restrict__ out) {
  __shared__ __align__(16) _Float16 Bs[2][64 * 64];   // 2 x 8 KB, [col][gp][e], gp = g ^ (col&7)

  const int tid = threadIdx.x, bid = blockIdx.x;
  const int kch = bid & 7;
  const int rest = bid >> 3;
  const int mt = rest & 7, nt = rest >> 3;
  const int b0 = mt * 512, n0 = nt * 64;
  const int w = tid >> 6, l = tid & 63;
  const int lm = l & 15, q = l >> 4;
  const int row0 = b0 + w * 128 + lm;    // + mm*16

  floatx4 acc[8][4] = {};

  // prologue: stage step 0 into buf 0 (wave w copies its 2 KB quarter)
  {
    const _Float16* slab = wpack + ((size_t)(kch * 32) * NCOL + n0) * 64 + (w << 10) + (l << 3);
    _Float16* dst = &Bs[0][0] + (w << 10);
    gload_lds16(slab, dst);
    gload_lds16(slab + 512, dst + 512);
  }

  for (int j = 0; j < 33; ++j) {
    const int s = (j < 32) ? (kch * 32 + j) : (256 + kch);

    __syncthreads();   // drains DMA(j) (in flight for a full step) + last step's ds_reads

    // --- table loads for step j, issued BEFORE next DMA (their waits leave DMA in flight) ---
    half8 eivr[8]; half2t erqr[8];
    half8 afs[8][2];
    if (j < 32) {
      #pragma unroll
      for (int mm = 0; mm < 8; ++mm) {
        size_t base = ((size_t)s * B_SZ + row0 + mm * 16) * 8;
        eivr[mm] = *(const half8*)(eivT + base);
        erqr[mm] = *(const half2t*)(erqT + base + (q << 1));
      }
    } else {
      #pragma unroll
      for (int mm = 0; mm < 8; ++mm) {
        const _Float16* p = sTab + (size_t)(row0 + mm * 16) * 512 + kch * 64 + (q << 3);
        afs[mm][0] = *(const half8*)p;
        afs[mm][1] = *(const half8*)(p + 32);
      }
    }

    // --- stage step j+1 into the other buffer (drained at NEXT barrier) ---
    if (j < 32) {
      const int s1 = (j < 31) ? (s + 1) : (256 + kch);
      const _Float16* slab = wpack + ((size_t)s1 * NCOL + n0) * 64 + (w << 10) + (l << 3);
      _Float16* dst = &Bs[(j + 1) & 1][0] + (w << 10);
      gload_lds16(slab, dst);
      gload_lds16(slab + 512, dst + 512);
    }

    // --- B fragments from current buffer (swizzled, conflict-free) ---
    half8 bf[4][2];
    const _Float16* bp0 = &Bs[j & 1][0];
    #pragma unroll
    for (int nn = 0; nn < 4; ++nn) {
      int c = nn * 16 + lm;
      const _Float16* bp = bp0 + (c << 6);
      bf[nn][0] = *(const half8*)(bp + ((q       ^ (c & 7)) << 3));
      bf[nn][1] = *(const half8*)(bp + (((q + 4) ^ (c & 7)) << 3));
    }

    // --- per m-frag: build A from tables (8 pk_mul) and run its 8 MFMAs ---
    #pragma unroll
    for (int mm = 0; mm < 8; ++mm) {
      half8 a0, a1;
      if (j < 32) {
        H8 ev; ev.v = eivr[mm];
        half2t e0 = {erqr[mm].x, erqr[mm].x};
        half2t e1 = {erqr[mm].y, erqr[mm].y};
        H8 r0, r1;
        #pragma unroll
        for (int t = 0; t < 4; ++t) { r0.h[t] = e0 * ev.h[t]; r1.h[t] = e1 * ev.h[t]; }
        a0 = r0.v; a1 = r1.v;
      } else {
        a0 = afs[mm][0]; a1 = afs[mm][1];
      }
      #pragma unroll
      for (int nn = 0; nn < 4; ++nn) {
        acc[mm][nn] = __builtin_amdgcn_mfma_f32_16x16x32_f16(a0, bf[nn][0], acc[mm][nn], 0, 0, 0);
        acc[mm][nn] = __builtin_amdgcn_mfma_f32_16x16x32_f16(a1, bf[nn][1], acc[mm][nn], 0, 0, 0);
      }
    }
  }

  // --- epilogue: C/D col=lane&15, row=q*4+reg; bias added by chunk-7 only ---
  #pragma unroll
  for (int nn = 0; nn < 4; ++nn) {
    int col = n0 + nn * 16 + lm;
    float bv = (kch == 7) ? bsum[col] : 0.0f;
    #pragma unroll
    for (int mm = 0; mm < 8; ++mm) {
      int r0 = b0 + w * 128 + mm * 16 + (q << 2);
      #pragma unroll
      for (int r2 = 0; r2 < 4; ++r2)
        atomicAdd(out + (size_t)(r0 + r2) * NCOL + col, acc[mm][nn][r2] + bv);
    }
  }
}

extern "C" void kernel_launch(void* const* d_in, const int* in_sizes, int n_in,
                              void* d_out, int out_size, void* d_ws, size_t ws_size,
                              hipStream_t stream) {
  const float* xre  = (const float*)d_in[0];
  const float* xim  = (const float*)d_in[1];
  const float* rw   = (const float*)d_in[2];
  const float* cw   = (const float*)d_in[3];
  const float* swre = (const float*)d_in[4];
  const float* swim = (const float*)d_in[5];
  const float* bre  = (const float*)d_in[6];
  const float* bim  = (const float*)d_in[7];
  float* out = (float*)d_out;

  size_t off = 0;
  _Float16* wpack = (_Float16*)((char*)d_ws + off); off += (size_t)KSTEPS * NCOL * 64 * 2;  // 16.5 MiB
  _Float16* eivT  = (_Float16*)((char*)d_ws + off); off += (size_t)I_SZ * B_SZ * 8 * 2;     // 16 MiB
  _Float16* erqT  = (_Float16*)((char*)d_ws + off); off += (size_t)I_SZ * B_SZ * 8 * 2;     // 16 MiB
  _Float16* sTab  = (_Float16*)((char*)d_ws + off); off += (size_t)B_SZ * 512 * 2;          // 4 MiB
  float*    bsum  = (float*)((char*)d_ws + off);

  prelude<<<5632, 256, 0, stream>>>(rw, cw, swre, swim, bre, bim, xre, xim,
                                    wpack, bsum, eivT, erqT, sTab, out);
  cvkan_gemm<<<512, 256, 0, stream>>>(eivT, erqT, sTab, wpack, bsum, out);
}

// Round 7
// 228.914 us; speedup vs baseline: 1.5412x; 1.0177x over previous
//
#include <hip/hip_runtime.h>
#include <stdint.h>

typedef float floatx4 __attribute__((ext_vector_type(4)));
typedef _Float16 half8 __attribute__((ext_vector_type(8)));
typedef _Float16 half2t __attribute__((ext_vector_type(2)));

constexpr int I_SZ = 256, O_SZ = 256, NCOL = 512, B_SZ = 4096;
constexpr int KSTEPS = 264;           // 256 RBF steps + 8 silu steps
constexpr float GSTEP = 4.0f / 7.0f;  // linspace(-2,2,8) step
constexpr float NLOG2E = -1.44269504088896f;

__device__ __forceinline__ float silu_f(float a) {
  return a * __builtin_amdgcn_rcpf(1.f + __builtin_amdgcn_exp2f(a * NLOG2E));
}
__device__ __forceinline__ void gload_lds16(const void* g, void* l) {
  __builtin_amdgcn_global_load_lds((const __attribute__((address_space(1))) void*)g,
                                   (__attribute__((address_space(3))) void*)l,
                                   16, 0, 0);
}

union H8 { half8 v; half2t h[4]; uint32_t u[4]; };

// ===== prelude (unchanged from R6) =====
__global__ void prelude(const float* __restrict__ rw, const float* __restrict__ cw,
                        const float* __restrict__ swre, const float* __restrict__ swim,
                        const float* __restrict__ bre, const float* __restrict__ bim,
                        const float* __restrict__ xre, const float* __restrict__ xim,
                        _Float16* __restrict__ wpack, float* __restrict__ bsum,
                        _Float16* __restrict__ eivT, _Float16* __restrict__ erqT,
                        _Float16* __restrict__ sTab, float* __restrict__ out) {
  __shared__ float tileR[64][65];
  __shared__ float tileI[64][65];
  const int bid = blockIdx.x, tid = threadIdx.x;

  if (bid < 4224) {
    int idx = bid * 256 + tid;                  // (kb, n, gp): 264*512*8
    int kb = idx >> 12;
    int rem = idx & 4095;
    int n = rem >> 3, gp = rem & 7;
    int g = gp ^ (n & 7);
    int o = n >> 1, c = n & 1;
    float w[8];
    if (kb < 256) {
      const float* W = (c ? cw : rw) + (((size_t)kb * O_SZ + o) << 6) + (g << 3);
      float4 a = *(const float4*)W;
      float4 b = *(const float4*)(W + 4);
      w[0] = a.x; w[1] = a.y; w[2] = a.z; w[3] = a.w;
      w[4] = b.x; w[5] = b.y; w[6] = b.z; w[7] = b.w;
    } else {
      int kp0 = ((kb - 256) << 6) + (g << 3);
      #pragma unroll
      for (int e = 0; e < 8; ++e) {
        int kp = kp0 + e, i = kp >> 1, ci = kp & 1;
        float a = swre[i * O_SZ + o], b = swim[i * O_SZ + o];
        w[e] = (c == 0) ? (ci == 0 ? a : -b) : (ci == 0 ? b : a);
      }
    }
    H8 val;
    #pragma unroll
    for (int e = 0; e < 8; ++e) val.v[e] = (_Float16)w[e];
    *(H8*)(wpack + (size_t)idx * 8) = val;
  } else if (bid < 4480) {
    // ---- exp tables: tile 64 i x 64 b ----
    int tb = bid - 4224;
    int bt = tb & 63, it = tb >> 6;
    int b0 = bt << 6, i0 = it << 6;
    int il = tid & 63, bh = tid >> 6;
    #pragma unroll
    for (int k = 0; k < 16; ++k) {
      int bl = bh + (k << 2);
      tileR[bl][il] = xre[(size_t)(b0 + bl) * I_SZ + i0 + il];
      tileI[bl][il] = xim[(size_t)(b0 + bl) * I_SZ + i0 + il];
    }
    __syncthreads();
    #pragma unroll
    for (int k = 0; k < 16; ++k) {
      int p = k * 256 + tid;
      int i_l = p >> 6, b_l = p & 63;
      float xr = tileR[b_l][i_l];
      float xi = tileI[b_l][i_l];
      float eru[8], eiv[8];
      #pragma unroll
      for (int g = 0; g < 8; ++g) {
        float dr = xr - (-2.0f + g * GSTEP);
        float di = xi - (-2.0f + g * GSTEP);
        eru[g] = __builtin_amdgcn_exp2f(dr * dr * NLOG2E);
        eiv[g] = __builtin_amdgcn_exp2f(di * di * NLOG2E);
      }
      size_t base = ((size_t)(i0 + i_l) * B_SZ + b0 + b_l) * 8;
      H8 ev, eq;
      #pragma unroll
      for (int g = 0; g < 8; ++g) ev.v[g] = (_Float16)eiv[g];
      #pragma unroll
      for (int q = 0; q < 4; ++q) { eq.v[2 * q] = (_Float16)eru[q]; eq.v[2 * q + 1] = (_Float16)eru[q + 4]; }
      *(H8*)(eivT + base) = ev;
      *(H8*)(erqT + base) = eq;
    }
  } else if (bid < 4992) {
    // ---- silu table: sTab[b][2i+ci] ----
    int tg = (bid - 4480) * 256 + tid;
    int b = tg >> 5, io = (tg & 31) << 3;
    const float* pr = xre + (size_t)b * I_SZ + io;
    const float* pi = xim + (size_t)b * I_SZ + io;
    float4 r0 = *(const float4*)pr, r1 = *(const float4*)(pr + 4);
    float4 q0 = *(const float4*)pi, q1 = *(const float4*)(pi + 4);
    H8 lo, hi;
    lo.v[0] = (_Float16)silu_f(r0.x); lo.v[1] = (_Float16)silu_f(q0.x);
    lo.v[2] = (_Float16)silu_f(r0.y); lo.v[3] = (_Float16)silu_f(q0.y);
    lo.v[4] = (_Float16)silu_f(r0.z); lo.v[5] = (_Float16)silu_f(q0.z);
    lo.v[6] = (_Float16)silu_f(r0.w); lo.v[7] = (_Float16)silu_f(q0.w);
    hi.v[0] = (_Float16)silu_f(r1.x); hi.v[1] = (_Float16)silu_f(q1.x);
    hi.v[2] = (_Float16)silu_f(r1.y); hi.v[3] = (_Float16)silu_f(q1.y);
    hi.v[4] = (_Float16)silu_f(r1.z); hi.v[5] = (_Float16)silu_f(q1.z);
    hi.v[6] = (_Float16)silu_f(r1.w); hi.v[7] = (_Float16)silu_f(q1.w);
    _Float16* dst = sTab + (size_t)b * 512 + 2 * io;
    *(H8*)dst = lo;
    *(H8*)(dst + 8) = hi;
  } else if (bid < 5120) {
    int w = tid >> 6, l = tid & 63;             // bias sums, one wave per n
    int n = (bid - 4992) * 4 + w;
    int o = n >> 1;
    const float* src = ((n & 1) ? bim : bre) + o;
    float s = 0.f;
    #pragma unroll
    for (int a = 0; a < 4; ++a) s += src[(size_t)(a * 64 + l) * O_SZ];
    #pragma unroll
    for (int off = 32; off; off >>= 1) s += __shfl_down(s, off, 64);
    if (l == 0) bsum[n] = s;
  } else {
    int z = bid - 5120;                         // zero d_out: 512 blk * 16 KB
    float4* o4 = (float4*)out;
    float4 zv = {0.f, 0.f, 0.f, 0.f};
    #pragma unroll
    for (int k = 0; k < 4; ++k) o4[(size_t)z * 1024 + k * 256 + tid] = zv;
  }
}

// ===== pipelined GEMM: B via LDS-DMA, tables via register prefetch (distance 1) =====
// grid 512 = kch(8, low bits) x mt(8) x nt(8). Block 256 = 4 waves; tile 512 rows x 64 cols.
// K-loop has ZERO exposed load latency: all global accesses issued one step before use,
// drained by the (compiler-emitted) vmcnt(0) at the NEXT barrier after a full step of work.
__global__ __launch_bounds__(256, 2) void cvkan_gemm(
    const _Float16* __restrict__ eivT, const _Float16* __restrict__ erqT,
    const _Float16* __restrict__ sTab,
    const _Float16* __restrict__ wpack, const float* __restrict__ bsum,
    float* __restrict__ out) {
  __shared__ __align__(16) _Float16 Bs[2][64 * 64];   // 2 x 8 KB, [col][gp][e], gp = g ^ (col&7)

  const int tid = threadIdx.x, bid = blockIdx.x;
  const int kch = bid & 7;
  const int rest = bid >> 3;
  const int mt = rest & 7, nt = rest >> 3;
  const int b0 = mt * 512, n0 = nt * 64;
  const int w = tid >> 6, l = tid & 63;
  const int lm = l & 15, q = l >> 4;
  const int row0 = b0 + w * 128 + lm;    // + mm*16

  floatx4 acc[8][4] = {};

  auto stageB = [&](int s, int buf) {
    const _Float16* slab = wpack + ((size_t)s * NCOL + n0) * 64 + (w << 10) + (l << 3);
    _Float16* dst = &Bs[buf][0] + (w << 10);
    gload_lds16(slab, dst);
    gload_lds16(slab + 512, dst + 512);
  };
  auto loadTabs = [&](int s, half8* eiv, half2t* erq) {
    #pragma unroll
    for (int mm = 0; mm < 8; ++mm) {
      size_t base = ((size_t)s * B_SZ + row0 + mm * 16) * 8;
      eiv[mm] = *(const half8*)(eivT + base);
      erq[mm] = *(const half2t*)(erqT + base + (q << 1));
    }
  };
  auto compute = [&](int buf, const half8* eiv, const half2t* erq) {
    half8 bf0[4], bf1[4];
    const _Float16* bp0 = &Bs[buf][0];
    #pragma unroll
    for (int nn = 0; nn < 4; ++nn) {
      int c = nn * 16 + lm;
      const _Float16* bp = bp0 + (c << 6);
      bf0[nn] = *(const half8*)(bp + ((q       ^ (c & 7)) << 3));
      bf1[nn] = *(const half8*)(bp + (((q + 4) ^ (c & 7)) << 3));
    }
    #pragma unroll
    for (int mm = 0; mm < 8; ++mm) {
      H8 ev; ev.v = eiv[mm];
      half2t e0 = {erq[mm].x, erq[mm].x};
      half2t e1 = {erq[mm].y, erq[mm].y};
      H8 r0, r1;
      #pragma unroll
      for (int t = 0; t < 4; ++t) { r0.h[t] = e0 * ev.h[t]; r1.h[t] = e1 * ev.h[t]; }
      #pragma unroll
      for (int nn = 0; nn < 4; ++nn) {
        acc[mm][nn] = __builtin_amdgcn_mfma_f32_16x16x32_f16(r0.v, bf0[nn], acc[mm][nn], 0, 0, 0);
        acc[mm][nn] = __builtin_amdgcn_mfma_f32_16x16x32_f16(r1.v, bf1[nn], acc[mm][nn], 0, 0, 0);
      }
    }
  };

  half8 eivC[8], eivN[8];
  half2t erqC[8], erqN[8];

  // prologue: stage step 0 (B + tables); drained/completed at the first barrier
  stageB(kch * 32, 0);
  loadTabs(kch * 32, eivC, erqC);

  #pragma unroll 1
  for (int jj = 0; jj < 16; ++jj) {
    const int s0 = kch * 32 + 2 * jj;
    // even half: compute s0 (buf0, C-regs); prefetch s0+1 (buf1, N-regs)
    __syncthreads();                       // drains DMA+tables issued one step ago
    stageB(s0 + 1, 1);
    loadTabs(s0 + 1, eivN, erqN);
    compute(0, eivC, erqC);
    // odd half: compute s0+1 (buf1, N-regs); prefetch s0+2 or silu-B (buf0, C-regs)
    __syncthreads();
    if (jj < 15) { stageB(s0 + 2, 0); loadTabs(s0 + 2, eivC, erqC); }
    else         { stageB(256 + kch, 0); }
    compute(1, eivN, erqN);
  }

  // silu step (s = 256+kch), B already staged in buf0; afs loaded here (one exposed wait)
  __syncthreads();
  {
    half8 bf0[4], bf1[4];
    const _Float16* bp0 = &Bs[0][0];
    #pragma unroll
    for (int nn = 0; nn < 4; ++nn) {
      int c = nn * 16 + lm;
      const _Float16* bp = bp0 + (c << 6);
      bf0[nn] = *(const half8*)(bp + ((q       ^ (c & 7)) << 3));
      bf1[nn] = *(const half8*)(bp + (((q + 4) ^ (c & 7)) << 3));
    }
    #pragma unroll
    for (int mm = 0; mm < 8; ++mm) {
      const _Float16* p = sTab + (size_t)(row0 + mm * 16) * 512 + kch * 64 + (q << 3);
      half8 a0 = *(const half8*)p;
      half8 a1 = *(const half8*)(p + 32);
      #pragma unroll
      for (int nn = 0; nn < 4; ++nn) {
        acc[mm][nn] = __builtin_amdgcn_mfma_f32_16x16x32_f16(a0, bf0[nn], acc[mm][nn], 0, 0, 0);
        acc[mm][nn] = __builtin_amdgcn_mfma_f32_16x16x32_f16(a1, bf1[nn], acc[mm][nn], 0, 0, 0);
      }
    }
  }

  // --- epilogue: C/D col=lane&15, row=q*4+reg; bias added by chunk-7 only ---
  #pragma unroll
  for (int nn = 0; nn < 4; ++nn) {
    int col = n0 + nn * 16 + lm;
    float bv = (kch == 7) ? bsum[col] : 0.0f;
    #pragma unroll
    for (int mm = 0; mm < 8; ++mm) {
      int r0 = b0 + w * 128 + mm * 16 + (q << 2);
      #pragma unroll
      for (int r2 = 0; r2 < 4; ++r2)
        atomicAdd(out + (size_t)(r0 + r2) * NCOL + col, acc[mm][nn][r2] + bv);
    }
  }
}

extern "C" void kernel_launch(void* const* d_in, const int* in_sizes, int n_in,
                              void* d_out, int out_size, void* d_ws, size_t ws_size,
                              hipStream_t stream) {
  const float* xre  = (const float*)d_in[0];
  const float* xim  = (const float*)d_in[1];
  const float* rw   = (const float*)d_in[2];
  const float* cw   = (const float*)d_in[3];
  const float* swre = (const float*)d_in[4];
  const float* swim = (const float*)d_in[5];
  const float* bre  = (const float*)d_in[6];
  const float* bim  = (const float*)d_in[7];
  float* out = (float*)d_out;

  size_t off = 0;
  _Float16* wpack = (_Float16*)((char*)d_ws + off); off += (size_t)KSTEPS * NCOL * 64 * 2;  // 16.5 MiB
  _Float16* eivT  = (_Float16*)((char*)d_ws + off); off += (size_t)I_SZ * B_SZ * 8 * 2;     // 16 MiB
  _Float16* erqT  = (_Float16*)((char*)d_ws + off); off += (size_t)I_SZ * B_SZ * 8 * 2;     // 16 MiB
  _Float16* sTab  = (_Float16*)((char*)d_ws + off); off += (size_t)B_SZ * 512 * 2;          // 4 MiB
  float*    bsum  = (float*)((char*)d_ws + off);

  prelude<<<5632, 256, 0, stream>>>(rw, cw, swre, swim, bre, bim, xre, xim,
                                    wpack, bsum, eivT, erqT, sTab, out);
  cvkan_gemm<<<512, 256, 0, stream>>>(eivT, erqT, sTab, wpack, bsum, out);
}

// Round 8
// 216.561 us; speedup vs baseline: 1.6291x; 1.0570x over previous
//
#include <hip/hip_runtime.h>
#include <stdint.h>

typedef float floatx4 __attribute__((ext_vector_type(4)));
typedef _Float16 half8 __attribute__((ext_vector_type(8)));
typedef _Float16 half2t __attribute__((ext_vector_type(2)));

constexpr int I_SZ = 256, O_SZ = 256, NCOL = 512, B_SZ = 4096;
constexpr int KSTEPS = 264;           // 256 RBF steps + 8 silu steps
constexpr float GSTEP = 4.0f / 7.0f;  // linspace(-2,2,8) step
constexpr float NLOG2E = -1.44269504088896f;
constexpr size_t PART_STRIDE = (size_t)B_SZ * NCOL;   // floats per split-K partial

__device__ __forceinline__ float silu_f(float a) {
  return a * __builtin_amdgcn_rcpf(1.f + __builtin_amdgcn_exp2f(a * NLOG2E));
}
__device__ __forceinline__ void gload_lds16(const void* g, void* l) {
  __builtin_amdgcn_global_load_lds((const __attribute__((address_space(1))) void*)g,
                                   (__attribute__((address_space(3))) void*)l,
                                   16, 0, 0);
}

union H8 { half8 v; half2t h[4]; uint32_t u[4]; };

// ===== prelude =====
// [0,4224): wpack[s][n][gp][e] f16, gp = g ^ (n&7)
// [4224,4480): eivT[i][b][8] + erqT[i][b][8] f16 (pairs (eru_q, eru_{q+4}) at dword q)
// [4480,4608): bias column sums
// [4608,5120): zero d_out (fallback path only — split path launches 4608 blocks)
__global__ void prelude(const float* __restrict__ rw, const float* __restrict__ cw,
                        const float* __restrict__ swre, const float* __restrict__ swim,
                        const float* __restrict__ bre, const float* __restrict__ bim,
                        const float* __restrict__ xre, const float* __restrict__ xim,
                        _Float16* __restrict__ wpack, float* __restrict__ bsum,
                        _Float16* __restrict__ eivT, _Float16* __restrict__ erqT,
                        float* __restrict__ out) {
  __shared__ float tileR[64][65];
  __shared__ float tileI[64][65];
  const int bid = blockIdx.x, tid = threadIdx.x;

  if (bid < 4224) {
    int idx = bid * 256 + tid;                  // (kb, n, gp): 264*512*8
    int kb = idx >> 12;
    int rem = idx & 4095;
    int n = rem >> 3, gp = rem & 7;
    int g = gp ^ (n & 7);
    int o = n >> 1, c = n & 1;
    float w[8];
    if (kb < 256) {
      const float* W = (c ? cw : rw) + (((size_t)kb * O_SZ + o) << 6) + (g << 3);
      float4 a = *(const float4*)W;
      float4 b = *(const float4*)(W + 4);
      w[0] = a.x; w[1] = a.y; w[2] = a.z; w[3] = a.w;
      w[4] = b.x; w[5] = b.y; w[6] = b.z; w[7] = b.w;
    } else {
      int kp0 = ((kb - 256) << 6) + (g << 3);
      #pragma unroll
      for (int e = 0; e < 8; ++e) {
        int kp = kp0 + e, i = kp >> 1, ci = kp & 1;
        float a = swre[i * O_SZ + o], b = swim[i * O_SZ + o];
        w[e] = (c == 0) ? (ci == 0 ? a : -b) : (ci == 0 ? b : a);
      }
    }
    H8 val;
    #pragma unroll
    for (int e = 0; e < 8; ++e) val.v[e] = (_Float16)w[e];
    *(H8*)(wpack + (size_t)idx * 8) = val;
  } else if (bid < 4480) {
    // ---- exp tables: tile 64 i x 64 b ----
    int tb = bid - 4224;
    int bt = tb & 63, it = tb >> 6;
    int b0 = bt << 6, i0 = it << 6;
    int il = tid & 63, bh = tid >> 6;
    #pragma unroll
    for (int k = 0; k < 16; ++k) {
      int bl = bh + (k << 2);
      tileR[bl][il] = xre[(size_t)(b0 + bl) * I_SZ + i0 + il];
      tileI[bl][il] = xim[(size_t)(b0 + bl) * I_SZ + i0 + il];
    }
    __syncthreads();
    #pragma unroll
    for (int k = 0; k < 16; ++k) {
      int p = k * 256 + tid;
      int i_l = p >> 6, b_l = p & 63;
      float xr = tileR[b_l][i_l];
      float xi = tileI[b_l][i_l];
      float eru[8], eiv[8];
      #pragma unroll
      for (int g = 0; g < 8; ++g) {
        float dr = xr - (-2.0f + g * GSTEP);
        float di = xi - (-2.0f + g * GSTEP);
        eru[g] = __builtin_amdgcn_exp2f(dr * dr * NLOG2E);
        eiv[g] = __builtin_amdgcn_exp2f(di * di * NLOG2E);
      }
      size_t base = ((size_t)(i0 + i_l) * B_SZ + b0 + b_l) * 8;
      H8 ev, eq;
      #pragma unroll
      for (int g = 0; g < 8; ++g) ev.v[g] = (_Float16)eiv[g];
      #pragma unroll
      for (int q = 0; q < 4; ++q) { eq.v[2 * q] = (_Float16)eru[q]; eq.v[2 * q + 1] = (_Float16)eru[q + 4]; }
      *(H8*)(eivT + base) = ev;
      *(H8*)(erqT + base) = eq;
    }
  } else if (bid < 4608) {
    int w = tid >> 6, l = tid & 63;             // bias sums, one wave per n
    int n = (bid - 4480) * 4 + w;
    int o = n >> 1;
    const float* src = ((n & 1) ? bim : bre) + o;
    float s = 0.f;
    #pragma unroll
    for (int a = 0; a < 4; ++a) s += src[(size_t)(a * 64 + l) * O_SZ];
    #pragma unroll
    for (int off = 32; off; off >>= 1) s += __shfl_down(s, off, 64);
    if (l == 0) bsum[n] = s;
  } else {
    int z = bid - 4608;                         // zero d_out (fallback only)
    float4* o4 = (float4*)out;
    float4 zv = {0.f, 0.f, 0.f, 0.f};
    #pragma unroll
    for (int k = 0; k < 4; ++k) o4[(size_t)z * 1024 + k * 256 + tid] = zv;
  }
}

// ===== pipelined GEMM: B via LDS-DMA ping-pong (1 barrier/step), tables from L1/L2 =====
// grid 1024 = kch(8, low bits -> XCD) x mt(16) x nt(8). Block 256 = 4 waves; tile 256 x 64.
// Wave w owns rows [b0+w*64, +64) (mm<4), all 64 cols (nn<4).
// Epilogue: streaming stores to per-kch partial buffers (no atomics) when use_split,
//           else atomicAdd fallback (bias at kch==7).
__global__ __launch_bounds__(256, 3) void cvkan_gemm(
    const _Float16* __restrict__ eivT, const _Float16* __restrict__ erqT,
    const float* __restrict__ xre, const float* __restrict__ xim,
    const _Float16* __restrict__ wpack, const float* __restrict__ bsum,
    float* __restrict__ part, float* __restrict__ out, int use_split) {
  __shared__ __align__(16) _Float16 Bs[2][64 * 64];   // 2 x 8 KB, [col][gp][e], gp = g ^ (col&7)

  const int tid = threadIdx.x, bid = blockIdx.x;
  const int kch = bid & 7;
  const int rest = bid >> 3;
  const int mt = rest & 15, nt = rest >> 4;
  const int b0 = mt * 256, n0 = nt * 64;
  const int w = tid >> 6, l = tid & 63;
  const int lm = l & 15, q = l >> 4;
  const int row0 = b0 + w * 64 + lm;    // + mm*16

  floatx4 acc[4][4] = {};

  auto stageB = [&](int s, int buf) {
    const _Float16* slab = wpack + ((size_t)s * NCOL + n0) * 64 + (w << 10) + (l << 3);
    _Float16* dst = &Bs[buf][0] + (w << 10);
    gload_lds16(slab, dst);
    gload_lds16(slab + 512, dst + 512);
  };

  // prologue: stage step 0 into buf 0
  stageB(kch * 32, 0);

  for (int j = 0; j < 33; ++j) {
    const int s = (j < 32) ? (kch * 32 + j) : (256 + kch);

    __syncthreads();   // drains DMA(j) (in flight since last step) + last step's ds_reads

    // --- A-source loads for step j, issued BEFORE the next DMA:
    //     waiting on them (vmcnt) leaves the younger DMA in flight ---
    half8 eivr[4]; half2t erqr[4];
    half8 afs[4][2];
    if (j < 32) {
      #pragma unroll
      for (int mm = 0; mm < 4; ++mm) {
        size_t base = ((size_t)s * B_SZ + row0 + mm * 16) * 8;
        eivr[mm] = *(const half8*)(eivT + base);
        erqr[mm] = *(const half2t*)(erqT + base + (q << 1));
      }
    } else {
      // silu step: kp = kch*64 + (q+4kh)*8 + e; i = kp>>1, e even->re, odd->im
      #pragma unroll
      for (int mm = 0; mm < 4; ++mm) {
        const int row = row0 + mm * 16;
        #pragma unroll
        for (int kh = 0; kh < 2; ++kh) {
          int i0 = kch * 32 + (q + kh * 4) * 4;
          float4 fr = *(const float4*)(xre + (size_t)row * I_SZ + i0);
          float4 fi = *(const float4*)(xim + (size_t)row * I_SZ + i0);
          H8 a;
          a.v[0] = (_Float16)silu_f(fr.x); a.v[1] = (_Float16)silu_f(fi.x);
          a.v[2] = (_Float16)silu_f(fr.y); a.v[3] = (_Float16)silu_f(fi.y);
          a.v[4] = (_Float16)silu_f(fr.z); a.v[5] = (_Float16)silu_f(fi.z);
          a.v[6] = (_Float16)silu_f(fr.w); a.v[7] = (_Float16)silu_f(fi.w);
          afs[mm][kh] = a.v;
        }
      }
    }

    // --- stage step j+1 (drained at NEXT barrier, a full step away) ---
    if (j < 32) stageB((j < 31) ? (s + 1) : (256 + kch), (j + 1) & 1);

    // --- B fragments from current buffer (swizzled, conflict-free) ---
    half8 bf0[4], bf1[4];
    const _Float16* bp0 = &Bs[j & 1][0];
    #pragma unroll
    for (int nn = 0; nn < 4; ++nn) {
      int c = nn * 16 + lm;
      const _Float16* bp = bp0 + (c << 6);
      bf0[nn] = *(const half8*)(bp + ((q       ^ (c & 7)) << 3));
      bf1[nn] = *(const half8*)(bp + (((q + 4) ^ (c & 7)) << 3));
    }

    // --- per m-frag: build A (8 pk_mul) and run 8 MFMAs ---
    #pragma unroll
    for (int mm = 0; mm < 4; ++mm) {
      half8 a0, a1;
      if (j < 32) {
        H8 ev; ev.v = eivr[mm];
        half2t e0 = {erqr[mm].x, erqr[mm].x};
        half2t e1 = {erqr[mm].y, erqr[mm].y};
        H8 r0, r1;
        #pragma unroll
        for (int t = 0; t < 4; ++t) { r0.h[t] = e0 * ev.h[t]; r1.h[t] = e1 * ev.h[t]; }
        a0 = r0.v; a1 = r1.v;
      } else {
        a0 = afs[mm][0]; a1 = afs[mm][1];
      }
      #pragma unroll
      for (int nn = 0; nn < 4; ++nn) {
        acc[mm][nn] = __builtin_amdgcn_mfma_f32_16x16x32_f16(a0, bf0[nn], acc[mm][nn], 0, 0, 0);
        acc[mm][nn] = __builtin_amdgcn_mfma_f32_16x16x32_f16(a1, bf1[nn], acc[mm][nn], 0, 0, 0);
      }
    }
  }

  // --- epilogue: C/D col=lane&15, row=q*4+reg ---
  if (use_split) {
    float* dst = part + (size_t)kch * PART_STRIDE;
    #pragma unroll
    for (int nn = 0; nn < 4; ++nn) {
      int col = n0 + nn * 16 + lm;
      #pragma unroll
      for (int mm = 0; mm < 4; ++mm) {
        int r0 = b0 + w * 64 + mm * 16 + (q << 2);
        #pragma unroll
        for (int r2 = 0; r2 < 4; ++r2)
          dst[(size_t)(r0 + r2) * NCOL + col] = acc[mm][nn][r2];
      }
    }
  } else {
    #pragma unroll
    for (int nn = 0; nn < 4; ++nn) {
      int col = n0 + nn * 16 + lm;
      float bv = (kch == 7) ? bsum[col] : 0.0f;
      #pragma unroll
      for (int mm = 0; mm < 4; ++mm) {
        int r0 = b0 + w * 64 + mm * 16 + (q << 2);
        #pragma unroll
        for (int r2 = 0; r2 < 4; ++r2)
          atomicAdd(out + (size_t)(r0 + r2) * NCOL + col, acc[mm][nn][r2] + bv);
      }
    }
  }
}

// ===== reduce: out = sum_k part[k] + bias (streaming, float4) =====
__global__ void reduce_k(const float* __restrict__ part, const float* __restrict__ bsum,
                         float* __restrict__ out) {
  size_t idx4 = (size_t)blockIdx.x * 256 + threadIdx.x;   // 2048 blocks * 256
  size_t base = idx4 * 4;
  int n = (int)(base & (NCOL - 1));
  float4 s = *(const float4*)(bsum + n);
  #pragma unroll
  for (int k = 0; k < 8; ++k) {
    float4 p = *(const float4*)(part + k * PART_STRIDE + base);
    s.x += p.x; s.y += p.y; s.z += p.z; s.w += p.w;
  }
  *(float4*)(out + base) = s;
}

extern "C" void kernel_launch(void* const* d_in, const int* in_sizes, int n_in,
                              void* d_out, int out_size, void* d_ws, size_t ws_size,
                              hipStream_t stream) {
  const float* xre  = (const float*)d_in[0];
  const float* xim  = (const float*)d_in[1];
  const float* rw   = (const float*)d_in[2];
  const float* cw   = (const float*)d_in[3];
  const float* swre = (const float*)d_in[4];
  const float* swim = (const float*)d_in[5];
  const float* bre  = (const float*)d_in[6];
  const float* bim  = (const float*)d_in[7];
  float* out = (float*)d_out;

  size_t off = 0;
  _Float16* wpack = (_Float16*)((char*)d_ws + off); off += (size_t)KSTEPS * NCOL * 64 * 2;  // 16.5 MiB
  _Float16* eivT  = (_Float16*)((char*)d_ws + off); off += (size_t)I_SZ * B_SZ * 8 * 2;     // 16 MiB
  _Float16* erqT  = (_Float16*)((char*)d_ws + off); off += (size_t)I_SZ * B_SZ * 8 * 2;     // 16 MiB
  float*    part  = (float*)((char*)d_ws + off);
  size_t part_bytes = 8 * PART_STRIDE * sizeof(float);                                       // 64 MiB
  size_t need_split = off + part_bytes + NCOL * sizeof(float);
  const bool use_split = (ws_size >= need_split);
  float* bsum = use_split ? (float*)((char*)d_ws + off + part_bytes)
                          : (float*)((char*)d_ws + off);

  prelude<<<use_split ? 4608 : 5120, 256, 0, stream>>>(
      rw, cw, swre, swim, bre, bim, xre, xim, wpack, bsum, eivT, erqT, out);
  cvkan_gemm<<<1024, 256, 0, stream>>>(eivT, erqT, xre, xim, wpack, bsum,
                                       part, out, (int)use_split);
  if (use_split)
    reduce_k<<<2048, 256, 0, stream>>>(part, bsum, out);
}